// Round 3
// baseline (5090.269 us; speedup 1.0000x reference)
//
#include <hip/hip_runtime.h>

// RNN: B=32, T=2048, E=256, H=256, L=2, f32.
//   A: xproj0 = x @ W0[0:256] + b0            -> d_out
//   B: layer-0 scan in-place on d_out
//   C: xproj1 = h0_all @ W1[0:256] + b1       (in-place, double-buffered LDS rows)
//   D: layer-1 scan in-place -> hidden_states; tail: ht
//
// Core pattern: 512 thr, p=tid&3, q=tid>>2, c=q&1 (i-half), j=(q>>1)*4+p.
// Lane holds 128 weights W[128c+i][j] in VGPRs (launch_bounds(512,2) => 256
// VGPR budget so they stay in arch VGPRs). Per 16-wide i-block: one
// ds_read_b128 per lane, 16 v_fmac_f32 with DPP quad-broadcast h operands
// (single-use qb<S> per FMA => folds to v_fmac_f32_dpp). LDS h halves padded
// to 144 floats so the two c-halves hit disjoint bank groups (conflict-free).
// Scan batches global xp-loads / h-stores in 4-step groups so 3 of 4 barriers
// have no outstanding VMEM (no vmcnt(0) drain).

#define TT 2048
#define BB 32
#define XPB 4
#define HPAD 144  // padded stride of one 128-float h half (128 + 16)

template <int S>
__device__ __forceinline__ float qb(float x) {
    constexpr int ctrl = S | (S << 2) | (S << 4) | (S << 6);  // quad_perm bcast S
    int r = __builtin_amdgcn_update_dpp(0, __float_as_int(x), ctrl, 0xF, 0xF, true);
    return __int_as_float(r);
}

#define QB4(S)                                          \
    a0 = fmaf(qb<S>(v.x), w[base + 4 * S + 0], a0);     \
    a1 = fmaf(qb<S>(v.y), w[base + 4 * S + 1], a1);     \
    a2 = fmaf(qb<S>(v.z), w[base + 4 * S + 2], a2);     \
    a3 = fmaf(qb<S>(v.w), w[base + 4 * S + 3], a3);

#define DOT128()                                                    \
    float a0 = 0.f, a1 = 0.f, a2 = 0.f, a3 = 0.f;                   \
    _Pragma("unroll")                                               \
    for (int k = 0; k < 8; ++k) {                                   \
        const int base = 16 * k;                                    \
        float4 v = *reinterpret_cast<const float4*>(hb + base + 4 * p); \
        QB4(0) QB4(1) QB4(2) QB4(3)                                 \
    }                                                               \
    float s = (a0 + a1) + (a2 + a3);                                \
    s += __shfl_xor(s, 4, 64);

// padded LDS index for h element i (i in [0,256))
__device__ __forceinline__ int hidx(int i) { return HPAD * (i >> 7) + (i & 127); }

__global__ __launch_bounds__(512, 2) void proj3_kernel(
    const float* in,                  // [R,256] (may alias out)
    const float* __restrict__ W,      // [512,256]; uses rows [0,256)
    const float* __restrict__ bias,   // [256]
    float* out,                       // [R,256]
    int rows_per_wg)
{
    __shared__ float rb[2][2 * HPAD];
    const int tid = threadIdx.x;
    const int p = tid & 3;
    const int q = tid >> 2;
    const int c = q & 1;
    const int j = (q >> 1) * 4 + p;

    float w[128];
#pragma unroll
    for (int i = 0; i < 128; ++i)
        w[i] = W[(size_t)(c * 128 + i) * 256 + j];
    const float bj = bias[j];

    const size_t r0 = (size_t)blockIdx.x * rows_per_wg;

    // stage row 0 (padded layout)
    if (tid < 64) {
        float4 t4 = reinterpret_cast<const float4*>(in + r0 * 256)[tid];
        *reinterpret_cast<float4*>(&rb[0][hidx(4 * tid)]) = t4;
    }
    __syncthreads();

    for (int rr = 0; rr < rows_per_wg; ++rr) {
        const int buf = rr & 1;
        if (rr + 1 < rows_per_wg && tid < 64) {
            float4 t4 = reinterpret_cast<const float4*>(in + (r0 + rr + 1) * 256)[tid];
            *reinterpret_cast<float4*>(&rb[buf ^ 1][hidx(4 * tid)]) = t4;
        }
        const float* hb = &rb[buf][HPAD * c];
        DOT128()
        if (c == 0) out[(r0 + rr) * 256 + j] = s + bj;
        __syncthreads();
    }
}

__global__ __launch_bounds__(512, 2) void scan3_kernel(
    const float* __restrict__ W,       // [512,256]; recurrent rows [256,512)
    const float* __restrict__ h_init,  // [B,256]
    float* __restrict__ io,            // [B,T,256] in: xproj rows, out: h rows
    float* __restrict__ hfinal)        // nullptr or [B,256]
{
    __shared__ float hbuf[2][2 * HPAD];
    const int tid = threadIdx.x;
    const int p = tid & 3;
    const int q = tid >> 2;
    const int c = q & 1;
    const int j = (q >> 1) * 4 + p;
    const int b = blockIdx.x;
    const bool wr = (c == 0);

    float w[128];
#pragma unroll
    for (int i = 0; i < 128; ++i)
        w[i] = W[(size_t)(256 + c * 128 + i) * 256 + j];

    if (tid < 256) hbuf[0][hidx(tid)] = h_init[b * 256 + tid];

    float* iob = io + (size_t)b * TT * 256;

    float xpc[XPB], xpn[XPB], hs[XPB];
    if (wr) {
#pragma unroll
        for (int u = 0; u < XPB; ++u) xpc[u] = iob[(size_t)u * 256 + j];
    }
    __syncthreads();

    for (int t0 = 0; t0 < TT; t0 += XPB) {
        const bool more = (t0 + XPB) < TT;
        if (wr && more) {
#pragma unroll
            for (int u = 0; u < XPB; ++u)
                xpn[u] = iob[(size_t)(t0 + XPB + u) * 256 + j];
        }
#pragma unroll
        for (int u = 0; u < XPB; ++u) {
            const int t = t0 + u;
            const float* hb = &hbuf[t & 1][HPAD * c];
            DOT128()
            if (wr) {
                const float z = s + xpc[u];
                const float e = __expf(2.0f * z);
                const float hn = 1.0f - 2.0f / (e + 1.0f);
                hbuf[(t + 1) & 1][hidx(j)] = hn;
                hs[u] = hn;
            }
            __syncthreads();
        }
        if (wr) {
#pragma unroll
            for (int u = 0; u < XPB; ++u)
                iob[(size_t)(t0 + u) * 256 + j] = hs[u];
            if (hfinal != nullptr && t0 == TT - XPB)
                hfinal[b * 256 + j] = hs[XPB - 1];
        }
        if (more) {
#pragma unroll
            for (int u = 0; u < XPB; ++u) xpc[u] = xpn[u];
        }
    }
}

extern "C" void kernel_launch(void* const* d_in, const int* in_sizes, int n_in,
                              void* d_out, int out_size, void* d_ws, size_t ws_size,
                              hipStream_t stream) {
    const float* x  = (const float*)d_in[0];  // [B,T,256]
    const float* h0 = (const float*)d_in[1];  // [2,B,256]
    const float* W0 = (const float*)d_in[2];  // [512,256]
    const float* b0 = (const float*)d_in[3];  // [256]
    const float* W1 = (const float*)d_in[4];  // [512,256]
    const float* b1 = (const float*)d_in[5];  // [256]
    float* out = (float*)d_out;               // [B*T*256] + [B*256]

    const int R = BB * TT;            // 65536
    const int NWG = 512;
    const int rows_per_wg = R / NWG;  // 128

    proj3_kernel<<<NWG, 512, 0, stream>>>(x, W0, b0, out, rows_per_wg);
    scan3_kernel<<<BB, 512, 0, stream>>>(W0, h0, out, nullptr);
    proj3_kernel<<<NWG, 512, 0, stream>>>(out, W1, b1, out, rows_per_wg);
    scan3_kernel<<<BB, 512, 0, stream>>>(W1, h0 + BB * 256, out,
                                         out + (size_t)BB * TT * 256);
}

// Round 4
// 3590.094 us; speedup vs baseline: 1.4179x; 1.4179x over previous
//
#include <hip/hip_runtime.h>

// RNN: B=32, T=2048, E=256, H=256, L=2, f32.
//   A: xproj0 = x @ W0[0:256] + b0            -> d_out
//   B: layer-0 scan in-place on d_out
//   C: xproj1 = h0_all @ W1[0:256] + b1       (in-place, double-buffered LDS rows)
//   D: layer-1 scan in-place -> hidden_states; tail: ht
//
// Core: 512 thr, p=tid&3, q=tid>>2, c=q&1 (i-half), j=(q>>1)*4+p.
// Lane holds 128 weights W[128c+i][j] in ARCH VGPRs (forced by inline-asm "v"
// constraints). Per 16-wide i-block: one ds_read_b128 per lane, then 16
// inline-asm v_fmac_f32_dpp with quad_perm broadcast of the h operand — the
// DPP is folded INTO the FMA (1 VALU inst per FMA, no separate mov, no AGPR
// round-trip). LDS h halves padded (stride 144) => conflict-free.
// Scan batches global xp-loads / h-stores in 4-step groups.

#define TT 2048
#define BB 32
#define XPB 4
#define HPAD 144  // padded stride of one 128-float h half

// one folded broadcast-FMA: acc += (quad-lane S's hv) * wv
#define FMAC1(acc, hv, wv, QPS)                                               \
    asm("v_fmac_f32_dpp %0, %1, %2 quad_perm:[" QPS "] row_mask:0xf "         \
        "bank_mask:0xf"                                                       \
        : "+v"(acc)                                                           \
        : "v"(hv), "v"(wv))

#define QBLK(S, QPS)                          \
    FMAC1(a0, v.x, w[base + 4 * S + 0], QPS); \
    FMAC1(a1, v.y, w[base + 4 * S + 1], QPS); \
    FMAC1(a2, v.z, w[base + 4 * S + 2], QPS); \
    FMAC1(a3, v.w, w[base + 4 * S + 3], QPS);

#define DOT128()                                                        \
    float a0 = 0.f, a1 = 0.f, a2 = 0.f, a3 = 0.f;                       \
    _Pragma("unroll")                                                   \
    for (int k = 0; k < 8; ++k) {                                       \
        const int base = 16 * k;                                        \
        float4 v = *reinterpret_cast<const float4*>(hb + base + 4 * p); \
        QBLK(0, "0,0,0,0")                                              \
        QBLK(1, "1,1,1,1")                                              \
        QBLK(2, "2,2,2,2")                                              \
        QBLK(3, "3,3,3,3")                                              \
    }                                                                   \
    float s = (a0 + a1) + (a2 + a3);                                    \
    s += __shfl_xor(s, 4, 64);

// padded LDS index for h element i (i in [0,256))
__device__ __forceinline__ int hidx(int i) { return HPAD * (i >> 7) + (i & 127); }

__global__ __launch_bounds__(512, 2) void proj4_kernel(
    const float* in,                  // [R,256] (may alias out)
    const float* __restrict__ W,      // [512,256]; uses rows [0,256)
    const float* __restrict__ bias,   // [256]
    float* out,                       // [R,256]
    int rows_per_wg)
{
    __shared__ float rb[2][2 * HPAD];
    const int tid = threadIdx.x;
    const int p = tid & 3;
    const int q = tid >> 2;
    const int c = q & 1;
    const int j = (q >> 1) * 4 + p;

    float w[128];
#pragma unroll
    for (int i = 0; i < 128; ++i)
        w[i] = W[(size_t)(c * 128 + i) * 256 + j];
    const float bj = bias[j];

    const size_t r0 = (size_t)blockIdx.x * rows_per_wg;

    if (tid < 64) {
        float4 t4 = reinterpret_cast<const float4*>(in + r0 * 256)[tid];
        *reinterpret_cast<float4*>(&rb[0][hidx(4 * tid)]) = t4;
    }
    __syncthreads();

    for (int rr = 0; rr < rows_per_wg; ++rr) {
        const int buf = rr & 1;
        if (rr + 1 < rows_per_wg && tid < 64) {
            float4 t4 = reinterpret_cast<const float4*>(in + (r0 + rr + 1) * 256)[tid];
            *reinterpret_cast<float4*>(&rb[buf ^ 1][hidx(4 * tid)]) = t4;
        }
        const float* hb = &rb[buf][HPAD * c];
        DOT128()
        if (c == 0) out[(r0 + rr) * 256 + j] = s + bj;
        __syncthreads();
    }
}

__global__ __launch_bounds__(512, 2) void scan4_kernel(
    const float* __restrict__ W,       // [512,256]; recurrent rows [256,512)
    const float* __restrict__ h_init,  // [B,256]
    float* __restrict__ io,            // [B,T,256] in: xproj rows, out: h rows
    float* __restrict__ hfinal)        // nullptr or [B,256]
{
    __shared__ float hbuf[2][2 * HPAD];
    const int tid = threadIdx.x;
    const int p = tid & 3;
    const int q = tid >> 2;
    const int c = q & 1;
    const int j = (q >> 1) * 4 + p;
    const int b = blockIdx.x;
    const bool wr = (c == 0);

    float w[128];
#pragma unroll
    for (int i = 0; i < 128; ++i)
        w[i] = W[(size_t)(256 + c * 128 + i) * 256 + j];

    if (tid < 256) hbuf[0][hidx(tid)] = h_init[b * 256 + tid];

    float* iob = io + (size_t)b * TT * 256;

    float xpc[XPB], xpn[XPB], hs[XPB];
    if (wr) {
#pragma unroll
        for (int u = 0; u < XPB; ++u) xpc[u] = iob[(size_t)u * 256 + j];
    }
    __syncthreads();

    for (int t0 = 0; t0 < TT; t0 += XPB) {
        const bool more = (t0 + XPB) < TT;
        if (wr && more) {
#pragma unroll
            for (int u = 0; u < XPB; ++u)
                xpn[u] = iob[(size_t)(t0 + XPB + u) * 256 + j];
        }
#pragma unroll
        for (int u = 0; u < XPB; ++u) {
            const int t = t0 + u;
            const float* hb = &hbuf[t & 1][HPAD * c];
            DOT128()
            if (wr) {
                const float z = s + xpc[u];
                const float e = __expf(2.0f * z);
                const float hn = 1.0f - 2.0f / (e + 1.0f);
                hbuf[(t + 1) & 1][hidx(j)] = hn;
                hs[u] = hn;
            }
            __syncthreads();
        }
        if (wr) {
#pragma unroll
            for (int u = 0; u < XPB; ++u)
                iob[(size_t)(t0 + u) * 256 + j] = hs[u];
            if (hfinal != nullptr && t0 == TT - XPB)
                hfinal[b * 256 + j] = hs[XPB - 1];
        }
        if (more) {
#pragma unroll
            for (int u = 0; u < XPB; ++u) xpc[u] = xpn[u];
        }
    }
}

extern "C" void kernel_launch(void* const* d_in, const int* in_sizes, int n_in,
                              void* d_out, int out_size, void* d_ws, size_t ws_size,
                              hipStream_t stream) {
    const float* x  = (const float*)d_in[0];  // [B,T,256]
    const float* h0 = (const float*)d_in[1];  // [2,B,256]
    const float* W0 = (const float*)d_in[2];  // [512,256]
    const float* b0 = (const float*)d_in[3];  // [256]
    const float* W1 = (const float*)d_in[4];  // [512,256]
    const float* b1 = (const float*)d_in[5];  // [256]
    float* out = (float*)d_out;               // [B*T*256] + [B*256]

    const int R = BB * TT;            // 65536
    const int NWG = 512;
    const int rows_per_wg = R / NWG;  // 128

    proj4_kernel<<<NWG, 512, 0, stream>>>(x, W0, b0, out, rows_per_wg);
    scan4_kernel<<<BB, 512, 0, stream>>>(W0, h0, out, nullptr);
    proj4_kernel<<<NWG, 512, 0, stream>>>(out, W1, b1, out, rows_per_wg);
    scan4_kernel<<<BB, 512, 0, stream>>>(W1, h0 + BB * 256, out,
                                         out + (size_t)BB * TT * 256);
}

// Round 6
// 3511.945 us; speedup vs baseline: 1.4494x; 1.0223x over previous
//
#include <hip/hip_runtime.h>

// RNN: B=32, T=2048, E=256, H=256, L=2, f32.
//   A: xproj0 = x @ W0[0:256] + b0            -> d_out
//   B: layer-0 scan in-place on d_out
//   C: xproj1 = h0_all @ W1[0:256] + b1       (in-place, double-buffered LDS rows)
//   D: layer-1 scan in-place -> hidden_states; tail: ht
//
// Core (round-4-PROVEN mapping): 512 thr, p=tid&3, q=tid>>2, c=q&1 (i-half),
// j=(q>>1)*4+p. Lane holds 128 weights W[128c+i][j]; amdgpu_waves_per_eu(2,2)
// pins occupancy at 2 waves/EU (1 block/CU) so the register allocator has a
// 256-VGPR budget and no occupancy incentive to shunt w[] into AGPRs (round-4's
// VGPR_Count=84 meant every FMA paid a v_accvgpr_read copy).
// Per 16-wide i-block: one ds_read_b128 per lane, 16 v_fmac_f32_dpp with
// quad_perm broadcast folded into the FMA. i-half reduce = __shfl_xor(4)
// (proven). LDS h halves padded (stride 144) => conflict-free.
// Scan loop barrier = "s_waitcnt lgkmcnt(0); s_barrier": all cross-wave
// traffic in the loop is LDS (drained by lgkmcnt(0)); global xp-loads/h-stores
// are lane-private (stores touch rows <= t, loads rows > t, same lane+col) so
// they may stay in flight across barriers — no vmcnt(0) drains.
// Global I/O batched in 8-step groups.

#define TT 2048
#define BB 32
#define XPB 8
#define HPAD 144  // padded stride of one 128-float h half

// one folded broadcast-FMA: acc += (quad-lane S's hv) * wv
#define FMAC1(acc, hv, wv, QPS)                                               \
    asm("v_fmac_f32_dpp %0, %1, %2 quad_perm:[" QPS "] row_mask:0xf "         \
        "bank_mask:0xf"                                                       \
        : "+v"(acc)                                                           \
        : "v"(hv), "v"(wv))

#define QBLK(S, QPS)                          \
    FMAC1(a0, v.x, w[base + 4 * S + 0], QPS); \
    FMAC1(a1, v.y, w[base + 4 * S + 1], QPS); \
    FMAC1(a2, v.z, w[base + 4 * S + 2], QPS); \
    FMAC1(a3, v.w, w[base + 4 * S + 3], QPS);

// full 128-dot + cross-half reduce; leaves total in `s` (valid in all lanes)
#define DOT128()                                                        \
    float a0 = 0.f, a1 = 0.f, a2 = 0.f, a3 = 0.f;                       \
    _Pragma("unroll")                                                   \
    for (int k = 0; k < 8; ++k) {                                       \
        const int base = 16 * k;                                        \
        float4 v = *reinterpret_cast<const float4*>(hb + base + 4 * p); \
        QBLK(0, "0,0,0,0")                                              \
        QBLK(1, "1,1,1,1")                                              \
        QBLK(2, "2,2,2,2")                                              \
        QBLK(3, "3,3,3,3")                                              \
    }                                                                   \
    float s = (a0 + a1) + (a2 + a3);                                    \
    s += __shfl_xor(s, 4, 64);

// LDS-only barrier: drain own LDS ops, then barrier. Global ops stay in flight.
#define LDS_BARRIER() asm volatile("s_waitcnt lgkmcnt(0)\n\ts_barrier" ::: "memory")

// padded LDS index for h element i (i in [0,256))
__device__ __forceinline__ int hidx(int i) { return HPAD * (i >> 7) + (i & 127); }

__global__ __launch_bounds__(512)
__attribute__((amdgpu_waves_per_eu(2, 2))) void proj6_kernel(
    const float* in,                  // [R,256] (may alias out)
    const float* __restrict__ W,      // [512,256]; uses rows [0,256)
    const float* __restrict__ bias,   // [256]
    float* out,                       // [R,256]
    int rows_per_wg)
{
    __shared__ float rb[2][2 * HPAD];
    const int tid = threadIdx.x;
    const int p = tid & 3;
    const int q = tid >> 2;
    const int c = q & 1;
    const int j = (q >> 1) * 4 + p;

    float w[128];
#pragma unroll
    for (int i = 0; i < 128; ++i)
        w[i] = W[(size_t)(c * 128 + i) * 256 + j];
    const float bj = bias[j];

    const size_t r0 = (size_t)blockIdx.x * rows_per_wg;

    if (tid < 64) {
        float4 t4 = reinterpret_cast<const float4*>(in + r0 * 256)[tid];
        *reinterpret_cast<float4*>(&rb[0][hidx(4 * tid)]) = t4;
    }
    __syncthreads();

    for (int rr = 0; rr < rows_per_wg; ++rr) {
        const int buf = rr & 1;
        if (rr + 1 < rows_per_wg && tid < 64) {
            float4 t4 = reinterpret_cast<const float4*>(in + (r0 + rr + 1) * 256)[tid];
            *reinterpret_cast<float4*>(&rb[buf ^ 1][hidx(4 * tid)]) = t4;
        }
        const float* hb = &rb[buf][HPAD * c];
        DOT128()
        if (c == 0) out[(r0 + rr) * 256 + j] = s + bj;
        // full barrier (vmcnt drain) required: in==out aliasing means next
        // row's global read must complete before that row can be overwritten.
        __syncthreads();
    }
}

__global__ __launch_bounds__(512)
__attribute__((amdgpu_waves_per_eu(2, 2))) void scan6_kernel(
    const float* __restrict__ W,       // [512,256]; recurrent rows [256,512)
    const float* __restrict__ h_init,  // [B,256]
    float* __restrict__ io,            // [B,T,256] in: xproj rows, out: h rows
    float* __restrict__ hfinal)        // nullptr or [B,256]
{
    __shared__ float hbuf[2][2 * HPAD];
    const int tid = threadIdx.x;
    const int p = tid & 3;
    const int q = tid >> 2;
    const int c = q & 1;
    const int j = (q >> 1) * 4 + p;
    const int b = blockIdx.x;
    const bool wr = (c == 0);

    float w[128];
#pragma unroll
    for (int i = 0; i < 128; ++i)
        w[i] = W[(size_t)(256 + c * 128 + i) * 256 + j];

    if (tid < 256) hbuf[0][hidx(tid)] = h_init[b * 256 + tid];

    float* iob = io + (size_t)b * TT * 256;

    float xpc[XPB], xpn[XPB], hs[XPB];
    if (wr) {
#pragma unroll
        for (int u = 0; u < XPB; ++u) xpc[u] = iob[(size_t)u * 256 + j];
    }
    __syncthreads();

    for (int t0 = 0; t0 < TT; t0 += XPB) {
        const bool more = (t0 + XPB) < TT;
        if (wr && more) {
#pragma unroll
            for (int u = 0; u < XPB; ++u)
                xpn[u] = iob[(size_t)(t0 + XPB + u) * 256 + j];
        }
#pragma unroll
        for (int u = 0; u < XPB; ++u) {
            const int t = t0 + u;
            const float* hb = &hbuf[t & 1][HPAD * c];
            DOT128()
            if (wr) {
                const float z = s + xpc[u];
                const float e = __expf(2.0f * z);
                const float hn = 1.0f - 2.0f / (e + 1.0f);
                hbuf[(t + 1) & 1][hidx(j)] = hn;
                hs[u] = hn;
            }
            LDS_BARRIER();
        }
        if (wr) {
#pragma unroll
            for (int u = 0; u < XPB; ++u)
                iob[(size_t)(t0 + u) * 256 + j] = hs[u];
            if (hfinal != nullptr && t0 == TT - XPB)
                hfinal[b * 256 + j] = hs[XPB - 1];
        }
        if (more) {
#pragma unroll
            for (int u = 0; u < XPB; ++u) xpc[u] = xpn[u];
        }
    }
}

extern "C" void kernel_launch(void* const* d_in, const int* in_sizes, int n_in,
                              void* d_out, int out_size, void* d_ws, size_t ws_size,
                              hipStream_t stream) {
    const float* x  = (const float*)d_in[0];  // [B,T,256]
    const float* h0 = (const float*)d_in[1];  // [2,B,256]
    const float* W0 = (const float*)d_in[2];  // [512,256]
    const float* b0 = (const float*)d_in[3];  // [256]
    const float* W1 = (const float*)d_in[4];  // [512,256]
    const float* b1 = (const float*)d_in[5];  // [256]
    float* out = (float*)d_out;               // [B*T*256] + [B*256]

    const int R = BB * TT;            // 65536
    const int NWG = 256;              // 1 block/CU
    const int rows_per_wg = R / NWG;  // 256

    proj6_kernel<<<NWG, 512, 0, stream>>>(x, W0, b0, out, rows_per_wg);
    scan6_kernel<<<BB, 512, 0, stream>>>(W0, h0, out, nullptr);
    proj6_kernel<<<NWG, 512, 0, stream>>>(out, W1, b1, out, rows_per_wg);
    scan6_kernel<<<BB, 512, 0, stream>>>(W1, h0 + BB * 256, out,
                                         out + (size_t)BB * TT * 256);
}

// Round 8
// 2541.088 us; speedup vs baseline: 2.0032x; 1.3821x over previous
//
#include <hip/hip_runtime.h>

// RNN: B=32, T=2048, E=256, H=256, L=2, f32.
// Pipelined megakernel:
//   pre: proj0 = x @ W0x + b0 -> ws.A  (grid 256)
//   mega (128 blocks, all co-resident):
//     blk 0-31   L0 scan: h0_t = tanh(ws.A[t] + W0h h0_{t-1}) -> d_out rows;
//                publish flagL0[b]=t+64 every 64 steps (fence+release)
//     blk 32-95  chasers (2/batch): wait flagL0 >= chunk end; xproj1 row =
//                h0_row @ W1x + b1 -> OVERWRITE ws.A rows (safe: L0's fence
//                drained all its loads of those rows); release chunkdone
//     blk 96-127 L1 scan: wait chunkdone[chunk]; h1_t = tanh(ws.A[t] +
//                W1h h1_{t-1}) -> d_out rows (overwrites h0 after its
//                consumers are done); final ht at t=2047
// Dot core (proven rounds 4/6): 512 thr, p=tid&3, q=tid>>2, c=q&1, j=(q>>1)*4+p;
// 128 weights/lane, ds_read_b128 + v_fmac_f32_dpp quad broadcast, shfl_xor(4).
// Cross-block sync: agent-scope acquire/release atomics + __threadfence.
// Fallback: serial 4-kernel path (round 6) if ws_size < 64MB+flags.

#define TT 2048
#define BB 32
#define XPB 8
#define HPAD 144
#define CHUNK 64
#define NCHUNK (TT / CHUNK)  // 32

#define FMAC1(acc, hv, wv, QPS)                                               \
    asm("v_fmac_f32_dpp %0, %1, %2 quad_perm:[" QPS "] row_mask:0xf "         \
        "bank_mask:0xf"                                                       \
        : "+v"(acc)                                                           \
        : "v"(hv), "v"(wv))

#define QBLK(S, QPS)                          \
    FMAC1(a0, v.x, w[base + 4 * S + 0], QPS); \
    FMAC1(a1, v.y, w[base + 4 * S + 1], QPS); \
    FMAC1(a2, v.z, w[base + 4 * S + 2], QPS); \
    FMAC1(a3, v.w, w[base + 4 * S + 3], QPS);

#define DOT128()                                                        \
    float a0 = 0.f, a1 = 0.f, a2 = 0.f, a3 = 0.f;                       \
    _Pragma("unroll")                                                   \
    for (int k = 0; k < 8; ++k) {                                       \
        const int base = 16 * k;                                        \
        float4 v = *reinterpret_cast<const float4*>(hb + base + 4 * p); \
        QBLK(0, "0,0,0,0")                                              \
        QBLK(1, "1,1,1,1")                                              \
        QBLK(2, "2,2,2,2")                                              \
        QBLK(3, "3,3,3,3")                                              \
    }                                                                   \
    float s = (a0 + a1) + (a2 + a3);                                    \
    s += __shfl_xor(s, 4, 64);

#define LDS_BARRIER() asm volatile("s_waitcnt lgkmcnt(0)\n\ts_barrier" ::: "memory")

__device__ __forceinline__ int hidx(int i) { return HPAD * (i >> 7) + (i & 127); }

__device__ __forceinline__ int aload(int* p) {
    return __hip_atomic_load(p, __ATOMIC_ACQUIRE, __HIP_MEMORY_SCOPE_AGENT);
}
__device__ __forceinline__ void astore(int* p, int v) {
    __hip_atomic_store(p, v, __ATOMIC_RELEASE, __HIP_MEMORY_SCOPE_AGENT);
}

__global__ __launch_bounds__(512)
__attribute__((amdgpu_waves_per_eu(2, 2))) void proj8_kernel(
    const float* in, const float* __restrict__ W, const float* __restrict__ bias,
    float* out, int rows_per_wg)
{
    __shared__ float rb[2][2 * HPAD];
    const int tid = threadIdx.x;
    const int p = tid & 3;
    const int q = tid >> 2;
    const int c = q & 1;
    const int j = (q >> 1) * 4 + p;

    float w[128];
#pragma unroll
    for (int i = 0; i < 128; ++i)
        w[i] = W[(size_t)(c * 128 + i) * 256 + j];
    const float bj = bias[j];

    const size_t r0 = (size_t)blockIdx.x * rows_per_wg;
    if (tid < 64) {
        float4 t4 = reinterpret_cast<const float4*>(in + r0 * 256)[tid];
        *reinterpret_cast<float4*>(&rb[0][hidx(4 * tid)]) = t4;
    }
    __syncthreads();

    for (int rr = 0; rr < rows_per_wg; ++rr) {
        const int buf = rr & 1;
        if (rr + 1 < rows_per_wg && tid < 64) {
            float4 t4 = reinterpret_cast<const float4*>(in + (r0 + rr + 1) * 256)[tid];
            *reinterpret_cast<float4*>(&rb[buf ^ 1][hidx(4 * tid)]) = t4;
        }
        const float* hb = &rb[buf][HPAD * c];
        DOT128()
        if (c == 0) out[(r0 + rr) * 256 + j] = s + bj;
        __syncthreads();
    }
}

// serial fallback scan (round-6-proven)
__global__ __launch_bounds__(512)
__attribute__((amdgpu_waves_per_eu(2, 2))) void scan8_kernel(
    const float* __restrict__ W, const float* __restrict__ h_init,
    float* __restrict__ io, float* __restrict__ hfinal)
{
    __shared__ float hbuf[2][2 * HPAD];
    const int tid = threadIdx.x;
    const int p = tid & 3;
    const int q = tid >> 2;
    const int c = q & 1;
    const int j = (q >> 1) * 4 + p;
    const int b = blockIdx.x;
    const bool wr = (c == 0);

    float w[128];
#pragma unroll
    for (int i = 0; i < 128; ++i)
        w[i] = W[(size_t)(256 + c * 128 + i) * 256 + j];

    if (tid < 256) hbuf[0][hidx(tid)] = h_init[b * 256 + tid];

    float* iob = io + (size_t)b * TT * 256;
    float xpc[XPB], xpn[XPB], hs[XPB];
    if (wr) {
#pragma unroll
        for (int u = 0; u < XPB; ++u) xpc[u] = iob[(size_t)u * 256 + j];
    }
    __syncthreads();

    for (int t0 = 0; t0 < TT; t0 += XPB) {
        const bool more = (t0 + XPB) < TT;
        if (wr && more) {
#pragma unroll
            for (int u = 0; u < XPB; ++u)
                xpn[u] = iob[(size_t)(t0 + XPB + u) * 256 + j];
        }
#pragma unroll
        for (int u = 0; u < XPB; ++u) {
            const int t = t0 + u;
            const float* hb = &hbuf[t & 1][HPAD * c];
            DOT128()
            if (wr) {
                const float z = s + xpc[u];
                const float e = __expf(2.0f * z);
                const float hn = 1.0f - 2.0f / (e + 1.0f);
                hbuf[(t + 1) & 1][hidx(j)] = hn;
                hs[u] = hn;
            }
            LDS_BARRIER();
        }
        if (wr) {
#pragma unroll
            for (int u = 0; u < XPB; ++u)
                iob[(size_t)(t0 + u) * 256 + j] = hs[u];
            if (hfinal != nullptr && t0 == TT - XPB)
                hfinal[b * 256 + j] = hs[XPB - 1];
        }
        if (more) {
#pragma unroll
            for (int u = 0; u < XPB; ++u) xpc[u] = xpn[u];
        }
    }
}

__global__ __launch_bounds__(512)
__attribute__((amdgpu_waves_per_eu(2, 2))) void mega_kernel(
    const float* __restrict__ W0, const float* __restrict__ W1,
    const float* __restrict__ b1v, const float* __restrict__ h0init,
    float* xpA, float* out, int* flags)
{
    __shared__ float lds[2][2 * HPAD];
    const int tid = threadIdx.x;
    const int p = tid & 3;
    const int q = tid >> 2;
    const int c = q & 1;
    const int j = (q >> 1) * 4 + p;
    const bool wr = (c == 0);
    const int bid = blockIdx.x;
    int* flagL0 = flags;
    int* chunkdone = flags + BB;

    if (bid < BB || bid >= 3 * BB) {
        // ---- scan roles ----
        const bool isL0 = (bid < BB);
        const int b = isL0 ? bid : bid - 3 * BB;
        const float* W = isL0 ? W0 : W1;
        const float* h_init = isL0 ? h0init : (h0init + BB * 256);

        float w[128];
#pragma unroll
        for (int i = 0; i < 128; ++i)
            w[i] = W[(size_t)(256 + c * 128 + i) * 256 + j];

        if (tid < 256) lds[0][hidx(tid)] = h_init[b * 256 + tid];

        const float* xsrc = xpA + (size_t)b * TT * 256;
        float* hdst = out + (size_t)b * TT * 256;
        float xpc[XPB], xpn[XPB], hs[XPB];

        if (isL0) {
            if (wr) {
#pragma unroll
                for (int u = 0; u < XPB; ++u) xpc[u] = xsrc[(size_t)u * 256 + j];
            }
            __syncthreads();
            for (int t0 = 0; t0 < TT; t0 += XPB) {
                const bool more = (t0 + XPB) < TT;
                if (wr && more) {
#pragma unroll
                    for (int u = 0; u < XPB; ++u)
                        xpn[u] = xsrc[(size_t)(t0 + XPB + u) * 256 + j];
                }
#pragma unroll
                for (int u = 0; u < XPB; ++u) {
                    const int t = t0 + u;
                    const float* hb = &lds[t & 1][HPAD * c];
                    DOT128()
                    if (wr) {
                        const float z = s + xpc[u];
                        const float e = __expf(2.0f * z);
                        const float hn = 1.0f - 2.0f / (e + 1.0f);
                        lds[(t + 1) & 1][hidx(j)] = hn;
                        hs[u] = hn;
                    }
                    LDS_BARRIER();
                }
                if (wr) {
#pragma unroll
                    for (int u = 0; u < XPB; ++u)
                        hdst[(size_t)(t0 + u) * 256 + j] = hs[u];
                }
                if (((t0 + XPB) & (CHUNK - 1)) == 0) {
                    // h0 rows [t0+XPB-64, t0+XPB) stored; make visible, publish
                    __threadfence();
                    __syncthreads();
                    if (tid == 0) astore(&flagL0[b], t0 + XPB);
                }
                if (more) {
#pragma unroll
                    for (int u = 0; u < XPB; ++u) xpc[u] = xpn[u];
                }
            }
        } else {
            __syncthreads();
            for (int chunk = 0; chunk < NCHUNK; ++chunk) {
                const int tbase = chunk * CHUNK;
                while (aload(&chunkdone[b * NCHUNK + chunk]) == 0)
                    __builtin_amdgcn_s_sleep(1);
                if (wr) {
#pragma unroll
                    for (int u = 0; u < XPB; ++u)
                        xpc[u] = xsrc[(size_t)(tbase + u) * 256 + j];
                }
                for (int g = 0; g < CHUNK / XPB; ++g) {
                    const int t0 = tbase + g * XPB;
                    if (wr && g + 1 < CHUNK / XPB) {
#pragma unroll
                        for (int u = 0; u < XPB; ++u)
                            xpn[u] = xsrc[(size_t)(t0 + XPB + u) * 256 + j];
                    }
#pragma unroll
                    for (int u = 0; u < XPB; ++u) {
                        const int t = t0 + u;
                        const float* hb = &lds[t & 1][HPAD * c];
                        DOT128()
                        if (wr) {
                            const float z = s + xpc[u];
                            const float e = __expf(2.0f * z);
                            const float hn = 1.0f - 2.0f / (e + 1.0f);
                            lds[(t + 1) & 1][hidx(j)] = hn;
                            hs[u] = hn;
                        }
                        LDS_BARRIER();
                    }
                    if (wr) {
#pragma unroll
                        for (int u = 0; u < XPB; ++u)
                            hdst[(size_t)(t0 + u) * 256 + j] = hs[u];
                        if (t0 + XPB == TT)
                            out[(size_t)BB * TT * 256 + b * 256 + j] = hs[XPB - 1];
                    }
                    if (g + 1 < CHUNK / XPB) {
#pragma unroll
                        for (int u = 0; u < XPB; ++u) xpc[u] = xpn[u];
                    }
                }
            }
        }
    } else {
        // ---- proj1 chasers ----
        const int k = bid - BB;  // 0..63
        const int b = k >> 1;
        const int half = k & 1;

        float w[128];
#pragma unroll
        for (int i = 0; i < 128; ++i)
            w[i] = W1[(size_t)(c * 128 + i) * 256 + j];
        const float bj = b1v[j];

        for (int chunk = half; chunk < NCHUNK; chunk += 2) {
            while (aload(&flagL0[b]) < (chunk + 1) * CHUNK)
                __builtin_amdgcn_s_sleep(1);
            const int tbase = chunk * CHUNK;
            const float* src = out + ((size_t)b * TT + tbase) * 256;  // h0 rows
            float* dst = xpA + ((size_t)b * TT + tbase) * 256;        // xproj1

            if (tid < 64) {
                float4 t4 = reinterpret_cast<const float4*>(src)[tid];
                *reinterpret_cast<float4*>(&lds[0][hidx(4 * tid)]) = t4;
            }
            __syncthreads();
            for (int r = 0; r < CHUNK; ++r) {
                const int buf = r & 1;
                if (r + 1 < CHUNK && tid < 64) {
                    float4 t4 =
                        reinterpret_cast<const float4*>(src + (size_t)(r + 1) * 256)[tid];
                    *reinterpret_cast<float4*>(&lds[buf ^ 1][hidx(4 * tid)]) = t4;
                }
                const float* hb = &lds[buf][HPAD * c];
                DOT128()
                if (wr) dst[(size_t)r * 256 + j] = s + bj;
                __syncthreads();
            }
            __threadfence();
            __syncthreads();
            if (tid == 0) astore(&chunkdone[b * NCHUNK + chunk], 1);
        }
    }
}

extern "C" void kernel_launch(void* const* d_in, const int* in_sizes, int n_in,
                              void* d_out, int out_size, void* d_ws, size_t ws_size,
                              hipStream_t stream) {
    const float* x  = (const float*)d_in[0];  // [B,T,256]
    const float* h0 = (const float*)d_in[1];  // [2,B,256]
    const float* W0 = (const float*)d_in[2];  // [512,256]
    const float* b0 = (const float*)d_in[3];  // [256]
    const float* W1 = (const float*)d_in[4];  // [512,256]
    const float* b1 = (const float*)d_in[5];  // [256]
    float* out = (float*)d_out;               // [B*T*256] + [B*256]

    const size_t XPA_FLOATS = (size_t)BB * TT * 256;  // 16.7M floats = 64MB
    const size_t FLAG_BYTES = (size_t)(BB + BB * NCHUNK) * sizeof(int);
    const size_t NEEDED = XPA_FLOATS * 4 + FLAG_BYTES;

    if (ws_size >= NEEDED) {
        float* xpA = (float*)d_ws;
        int* flags = (int*)((char*)d_ws + XPA_FLOATS * 4);
        hipMemsetAsync(flags, 0, FLAG_BYTES, stream);
        proj8_kernel<<<256, 512, 0, stream>>>(x, W0, b0, xpA, 256);
        mega_kernel<<<4 * BB, 512, 0, stream>>>(W0, W1, b1, h0, xpA, out, flags);
    } else {
        // serial fallback (round-6 path, d_out in-place)
        proj8_kernel<<<256, 512, 0, stream>>>(x, W0, b0, out, 256);
        scan8_kernel<<<BB, 512, 0, stream>>>(W0, h0, out, nullptr);
        proj8_kernel<<<256, 512, 0, stream>>>(out, W1, b1, out, 256);
        scan8_kernel<<<BB, 512, 0, stream>>>(W1, h0 + BB * 256, out, out + XPA_FLOATS);
    }
}